// Round 4
// baseline (177.295 us; speedup 1.0000x reference)
//
#include <hip/hip_runtime.h>
#include <hip/hip_bf16.h>

#define PAD_V 8192
#define H1 512
#define H2 64
#define B_SZ 32
#define K_SZ 32
#define L_SZ 128

// ---------------------------------------------------------------------------
// Kernel 1: one bag per block, 512 threads (8 waves/block).
// embedding_bag_mean + prelu(a0) + [H1->H2 prelu(a1)] + [H2->H2 prelu(a2)]
// blocks 0..31: query bags; blocks 32..1055: poi bags.
// Also zero-inits the done-counter used by kernel 2's fused epilogue.
// ---------------------------------------------------------------------------
__global__ __launch_bounds__(512, 8) void emb_mlp_kernel(
    const int* __restrict__ qbf, const int* __restrict__ pbf,
    const float* __restrict__ codebook,
    const float* __restrict__ qW1, const float* __restrict__ qb1,
    const float* __restrict__ qW2, const float* __restrict__ qb2,
    const float* __restrict__ pW1, const float* __restrict__ pb1,
    const float* __restrict__ pW2, const float* __restrict__ pb2,
    const float* __restrict__ qa0p, const float* __restrict__ qa1p, const float* __restrict__ qa2p,
    const float* __restrict__ pa0p, const float* __restrict__ pa1p, const float* __restrict__ pa2p,
    float* __restrict__ qh_out, float* __restrict__ ph_out,
    unsigned int* __restrict__ done_cnt)
{
    const int tid = threadIdx.x;
    const bool is_q = (blockIdx.x < B_SZ);

    if (blockIdx.x == 0 && tid == 0) *done_cnt = 0u;  // flushed at kernel end

    const int* idx_base;
    int bag;
    const float *W1, *b1, *W2, *b2;
    float a0, a1, a2;
    float* out;
    if (is_q) {
        idx_base = qbf; bag = blockIdx.x;
        W1 = qW1; b1 = qb1; W2 = qW2; b2 = qb2;
        a0 = *qa0p; a1 = *qa1p; a2 = *qa2p;
        out = qh_out;
    } else {
        idx_base = pbf; bag = blockIdx.x - B_SZ;
        W1 = pW1; b1 = pb1; W2 = pW2; b2 = pb2;
        a0 = *pa0p; a1 = *pa1p; a2 = *pa2p;
        out = ph_out;
    }

    __shared__ int   s_idx[L_SZ];
    __shared__ int   s_cntp[2];
    __shared__ float s_red[3][L_SZ][4];   // quarters 1..3 partials, 6 KB
    __shared__ float s_x[H1];             // post-prelu mean embedding
    __shared__ float s_p1[16][H2];        // MLP partials, 4 KB
    __shared__ float s_h1[H2];

    if (tid < L_SZ) s_idx[tid] = idx_base[bag * L_SZ + tid];
    __syncthreads();

    if (tid < L_SZ) {
        unsigned long long bal = __ballot(s_idx[tid] != PAD_V);
        if ((tid & 63) == 0) s_cntp[tid >> 6] = __popcll(bal);
    }

    // gather: quarter q = tid>>7 owns 32 rows; g = tid&127 is the 16B chunk
    const int g = tid & 127;
    const int q = tid >> 7;
    const float4* cb4 = (const float4*)codebook;
    float ax = 0.f, ay = 0.f, az = 0.f, aw = 0.f;
    #pragma unroll 8
    for (int l = 0; l < 32; l++) {
        int v = s_idx[q * 32 + l];
        float m = (v != PAD_V) ? 1.0f : 0.0f;
        float4 r = cb4[(size_t)v * 128 + g];
        ax = fmaf(m, r.x, ax);
        ay = fmaf(m, r.y, ay);
        az = fmaf(m, r.z, az);
        aw = fmaf(m, r.w, aw);
    }
    if (q != 0) {
        s_red[q - 1][g][0] = ax; s_red[q - 1][g][1] = ay;
        s_red[q - 1][g][2] = az; s_red[q - 1][g][3] = aw;
    }
    __syncthreads();
    if (q == 0) {
        int cnt = s_cntp[0] + s_cntp[1];
        float inv = (cnt > 0) ? 1.0f / (float)cnt : 0.0f;
        float e0 = (ax + s_red[0][g][0] + s_red[1][g][0] + s_red[2][g][0]) * inv;
        float e1 = (ay + s_red[0][g][1] + s_red[1][g][1] + s_red[2][g][1]) * inv;
        float e2 = (az + s_red[0][g][2] + s_red[1][g][2] + s_red[2][g][2]) * inv;
        float e3 = (aw + s_red[0][g][3] + s_red[1][g][3] + s_red[2][g][3]) * inv;
        s_x[4 * g + 0] = (e0 >= 0.f) ? e0 : a0 * e0;
        s_x[4 * g + 1] = (e1 >= 0.f) ? e1 : a0 * e1;
        s_x[4 * g + 2] = (e2 >= 0.f) ? e2 : a0 * e2;
        s_x[4 * g + 3] = (e3 >= 0.f) ? e3 : a0 * e3;
    }
    __syncthreads();

    // layer 1: thread = (chunk ch = tid>>5 of 16, col-pair j2 = tid&31)
    // cols {2*j2, 2*j2+1}, i in [ch*32, ch*32+32). float2 weight loads.
    const int j2 = tid & 31;
    const int ch = tid >> 5;
    const float2* W1v = (const float2*)W1;
    {
        const int i0 = ch * 32;
        float s0 = 0.f, s1 = 0.f;
        #pragma unroll 8
        for (int i = 0; i < 32; i++) {
            float x = s_x[i0 + i];
            float2 w = W1v[(size_t)(i0 + i) * 32 + j2];
            s0 = fmaf(x, w.x, s0);
            s1 = fmaf(x, w.y, s1);
        }
        s_p1[ch][2 * j2]     = s0;
        s_p1[ch][2 * j2 + 1] = s1;
    }
    __syncthreads();
    if (tid < H2) {
        float s = b1[tid];
        #pragma unroll
        for (int r = 0; r < 16; r++) s += s_p1[r][tid];
        s_h1[tid] = (s >= 0.f) ? s : a1 * s;
    }
    __syncthreads();

    // layer 2: 16 chunks x 4 i's, float2 weight loads
    const float2* W2v = (const float2*)W2;
    {
        const int i0 = ch * 4;
        float s0 = 0.f, s1 = 0.f;
        #pragma unroll
        for (int i = 0; i < 4; i++) {
            float x = s_h1[i0 + i];
            float2 w = W2v[(size_t)(i0 + i) * 32 + j2];
            s0 = fmaf(x, w.x, s0);
            s1 = fmaf(x, w.y, s1);
        }
        s_p1[ch][2 * j2]     = s0;
        s_p1[ch][2 * j2 + 1] = s1;
    }
    __syncthreads();
    if (tid < H2) {
        float s = b2[tid];
        #pragma unroll
        for (int r = 0; r < 16; r++) s += s_p1[r][tid];
        s = (s >= 0.f) ? s : a2 * s;
        out[bag * H2 + tid] = s;
    }
}

// ---------------------------------------------------------------------------
// Kernel 2: one block per (b,k). Bitmap intersection + cooperative eval dots.
// The last block to finish runs the fused epilogue for all 1024 outputs.
// ---------------------------------------------------------------------------
__global__ __launch_bounds__(128) void text_sim_kernel(
    const int* __restrict__ qbf, const int* __restrict__ pbf,
    const float* __restrict__ q_eval, const float* __restrict__ p_eval,
    const float* __restrict__ qh_ws, const float* __restrict__ ph_ws,
    const float* __restrict__ ind_ap,
    const float* __restrict__ qloc, const float* __restrict__ ploc,
    const float* __restrict__ ap, const float* __restrict__ bp,
    const float* __restrict__ cp, const float* __restrict__ dp,
    float* __restrict__ text_out,
    unsigned int* __restrict__ done_cnt,
    float* __restrict__ out)
{
    const int blk = blockIdx.x;
    const int b   = blk >> 5;
    const int k   = blk & 31;
    const int tid = threadIdx.x;
    const int lane = tid & 63;
    const int wave = tid >> 6;

    __shared__ unsigned int bm[256];   // 8192-bit membership
    __shared__ float s_qh[H2];
    __shared__ float s_ph[H2];
    __shared__ int   s_hitv[L_SZ];
    __shared__ int   s_nh;
    __shared__ float s_wp[2];
    __shared__ int   s_last;

    bm[tid] = 0u; bm[tid + 128] = 0u;
    if (tid == 0) s_nh = 0;
    if (tid < H2)  s_qh[tid] = qh_ws[b * H2 + tid];
    else           s_ph[tid - H2] = ph_ws[(b * K_SZ + k) * H2 + (tid - H2)];

    int pv = pbf[(b * K_SZ + k) * L_SZ + tid];
    if ((unsigned)pv < (unsigned)PAD_V)
        atomicOr(&bm[pv >> 5], 1u << (pv & 31));
    __syncthreads();

    {
        int v = qbf[b * L_SZ + tid];
        bool hit = ((unsigned)v < (unsigned)PAD_V) &&
                   ((bm[v >> 5] >> (v & 31)) & 1u);
        if (hit) {
            int pos = atomicAdd(&s_nh, 1);
            s_hitv[pos] = v;
        }
    }
    __syncthreads();

    const int nh = s_nh;
    const float ind_a = *ind_ap;
    float local = 0.f;

    for (int hh = wave; hh < nh; hh += 2) {
        int v = s_hitv[hh];
        float qd = s_qh[lane] * q_eval[(size_t)v * H2 + lane];
        float pd = s_ph[lane] * p_eval[(size_t)v * H2 + lane];
        #pragma unroll
        for (int m = 1; m < 64; m <<= 1) {
            qd += __shfl_xor(qd, m);
            pd += __shfl_xor(pd, m);
        }
        qd = (qd >= 0.f) ? qd : ind_a * qd;
        pd = (pd >= 0.f) ? pd : ind_a * pd;
        local += (qd + 1.f) * (pd + 1.f);
    }
    if (lane == 0) s_wp[wave] = local;
    __syncthreads();

    if (tid == 0) {
        text_out[blk] = s_wp[0] + s_wp[1];
        __threadfence();                            // release: text visible device-wide
        unsigned int old = atomicAdd(done_cnt, 1u); // device-scope
        s_last = (old == (unsigned)(B_SZ * K_SZ - 1)) ? 1 : 0;
    }
    __syncthreads();
    if (!s_last) return;

    // ---- fused epilogue: only the last-finishing block gets here ----
    __threadfence();  // acquire: all other blocks' text stores now visible
    __shared__ float s_text[B_SZ * K_SZ];
    __shared__ float s_mx[B_SZ];
    for (int t = tid; t < B_SZ * K_SZ; t += 128) s_text[t] = text_out[t];
    __syncthreads();
    if (tid < B_SZ) {
        float m = s_text[tid * K_SZ];
        #pragma unroll
        for (int i = 1; i < K_SZ; i++) m = fmaxf(m, s_text[tid * K_SZ + i]);
        s_mx[tid] = m;
    }
    __syncthreads();

    const float A = *ap, Bb = *bp, C = *cp, D = *dp;
    for (int e = tid; e < B_SZ * K_SZ; e += 128) {
        int eb = e >> 5;
        float qx = qloc[eb * 2], qy = qloc[eb * 2 + 1];
        float px = ploc[e * 2],  py = ploc[e * 2 + 1];
        float dx = qx - px, dy = qy - py;
        float dist = sqrtf(dx * dx + dy * dy);
        float ds = -logf(dist + 1.0f);
        float mx = s_mx[eb];
        float ts = (2.0f * s_text[e] - mx) / (mx + 1e-6f);
        float sig = 1.0f / (1.0f + expf(-(A * ts + Bb)));
        out[e] = (C - sig) * (ds - D);
    }
}

extern "C" void kernel_launch(void* const* d_in, const int* in_sizes, int n_in,
                              void* d_out, int out_size, void* d_ws, size_t ws_size,
                              hipStream_t stream) {
    const int*   qbf      = (const int*)d_in[0];
    const int*   pbf      = (const int*)d_in[1];
    const float* qloc     = (const float*)d_in[2];
    const float* ploc     = (const float*)d_in[3];
    const float* codebook = (const float*)d_in[4];
    const float* qW1      = (const float*)d_in[5];
    const float* qb1      = (const float*)d_in[6];
    const float* qW2      = (const float*)d_in[7];
    const float* qb2      = (const float*)d_in[8];
    const float* pW1      = (const float*)d_in[9];
    const float* pb1      = (const float*)d_in[10];
    const float* pW2      = (const float*)d_in[11];
    const float* pb2      = (const float*)d_in[12];
    const float* q_eval   = (const float*)d_in[13];
    const float* p_eval   = (const float*)d_in[14];
    const float* qa0      = (const float*)d_in[15];
    const float* qa1      = (const float*)d_in[16];
    const float* qa2      = (const float*)d_in[17];
    const float* pa0      = (const float*)d_in[18];
    const float* pa1      = (const float*)d_in[19];
    const float* pa2      = (const float*)d_in[20];
    const float* ind_a    = (const float*)d_in[21];
    const float* a        = (const float*)d_in[22];
    const float* bsc      = (const float*)d_in[23];
    const float* c        = (const float*)d_in[24];
    const float* d        = (const float*)d_in[25];

    float* qh   = (float*)d_ws;                   // 32*64
    float* ph   = qh + B_SZ * H2;                 // 1024*64
    float* text = ph + B_SZ * K_SZ * H2;          // 1024
    unsigned int* done = (unsigned int*)(text + B_SZ * K_SZ);

    emb_mlp_kernel<<<B_SZ + B_SZ * K_SZ, 512, 0, stream>>>(
        qbf, pbf, codebook,
        qW1, qb1, qW2, qb2, pW1, pb1, pW2, pb2,
        qa0, qa1, qa2, pa0, pa1, pa2,
        qh, ph, done);

    text_sim_kernel<<<B_SZ * K_SZ, 128, 0, stream>>>(
        qbf, pbf, q_eval, p_eval, qh, ph, ind_a,
        qloc, ploc, a, bsc, c, d,
        text, done, (float*)d_out);
}

// Round 5
// 155.516 us; speedup vs baseline: 1.1400x; 1.1400x over previous
//
#include <hip/hip_runtime.h>
#include <hip/hip_bf16.h>

#define PAD_V 8192
#define H1 512
#define H2 64
#define B_SZ 32
#define K_SZ 32
#define L_SZ 128

// ---------------------------------------------------------------------------
// Kernel 1: one bag per block, 512 threads (8 waves -> ~full occupancy).
// embedding_bag_mean + prelu(a0) + [H1->H2 prelu(a1)] + [H2->H2 prelu(a2)]
// blocks 0..31: query bags; blocks 32..1055: poi bags.
// NOTE (R4 post-mortem): do NOT fuse the epilogue via device-scope
// done-counter — 1024 near-simultaneous device atomics + __threadfence
// cost ~+22 us. Separate tiny kernels are cheaper than device-scope sync.
// ---------------------------------------------------------------------------
__global__ __launch_bounds__(512, 8) void emb_mlp_kernel(
    const int* __restrict__ qbf, const int* __restrict__ pbf,
    const float* __restrict__ codebook,
    const float* __restrict__ qW1, const float* __restrict__ qb1,
    const float* __restrict__ qW2, const float* __restrict__ qb2,
    const float* __restrict__ pW1, const float* __restrict__ pb1,
    const float* __restrict__ pW2, const float* __restrict__ pb2,
    const float* __restrict__ qa0p, const float* __restrict__ qa1p, const float* __restrict__ qa2p,
    const float* __restrict__ pa0p, const float* __restrict__ pa1p, const float* __restrict__ pa2p,
    float* __restrict__ qh_out, float* __restrict__ ph_out)
{
    const int tid = threadIdx.x;
    const bool is_q = (blockIdx.x < B_SZ);

    const int* idx_base;
    int bag;
    const float *W1, *b1, *W2, *b2;
    float a0, a1, a2;
    float* out;
    if (is_q) {
        idx_base = qbf; bag = blockIdx.x;
        W1 = qW1; b1 = qb1; W2 = qW2; b2 = qb2;
        a0 = *qa0p; a1 = *qa1p; a2 = *qa2p;
        out = qh_out;
    } else {
        idx_base = pbf; bag = blockIdx.x - B_SZ;
        W1 = pW1; b1 = pb1; W2 = pW2; b2 = pb2;
        a0 = *pa0p; a1 = *pa1p; a2 = *pa2p;
        out = ph_out;
    }

    __shared__ int   s_idx[L_SZ];
    __shared__ int   s_cntp[2];
    __shared__ float s_red[3][L_SZ][4];   // quarters 1..3 partials, 6 KB
    __shared__ float s_x[H1];             // post-prelu mean embedding
    __shared__ float s_p1[8][H2];         // MLP partials, 2 KB
    __shared__ float s_h1[H2];

    // stage indices (128 ints)
    if (tid < L_SZ) s_idx[tid] = idx_base[bag * L_SZ + tid];
    __syncthreads();

    // count non-PAD via ballots on waves 0,1 (tid<128)
    if (tid < L_SZ) {
        unsigned long long bal = __ballot(s_idx[tid] != PAD_V);
        if ((tid & 63) == 0) s_cntp[tid >> 6] = __popcll(bal);
    }

    // gather: quarter q = tid>>7 owns 32 rows; g = tid&127 is the 16B chunk
    const int g = tid & 127;
    const int q = tid >> 7;
    const float4* cb4 = (const float4*)codebook;
    float ax = 0.f, ay = 0.f, az = 0.f, aw = 0.f;
    #pragma unroll 8
    for (int l = 0; l < 32; l++) {
        int v = s_idx[q * 32 + l];
        float m = (v != PAD_V) ? 1.0f : 0.0f;
        float4 r = cb4[(size_t)v * 128 + g];
        ax = fmaf(m, r.x, ax);
        ay = fmaf(m, r.y, ay);
        az = fmaf(m, r.z, az);
        aw = fmaf(m, r.w, aw);
    }
    if (q != 0) {
        s_red[q - 1][g][0] = ax; s_red[q - 1][g][1] = ay;
        s_red[q - 1][g][2] = az; s_red[q - 1][g][3] = aw;
    }
    __syncthreads();
    if (q == 0) {
        int cnt = s_cntp[0] + s_cntp[1];
        float inv = (cnt > 0) ? 1.0f / (float)cnt : 0.0f;
        float e0 = (ax + s_red[0][g][0] + s_red[1][g][0] + s_red[2][g][0]) * inv;
        float e1 = (ay + s_red[0][g][1] + s_red[1][g][1] + s_red[2][g][1]) * inv;
        float e2 = (az + s_red[0][g][2] + s_red[1][g][2] + s_red[2][g][2]) * inv;
        float e3 = (aw + s_red[0][g][3] + s_red[1][g][3] + s_red[2][g][3]) * inv;
        s_x[4 * g + 0] = (e0 >= 0.f) ? e0 : a0 * e0;
        s_x[4 * g + 1] = (e1 >= 0.f) ? e1 : a0 * e1;
        s_x[4 * g + 2] = (e2 >= 0.f) ? e2 : a0 * e2;
        s_x[4 * g + 3] = (e3 >= 0.f) ? e3 : a0 * e3;
    }
    __syncthreads();

    // layer 1: j = tid&63, i-chunk = tid>>6 (8 chunks x 64 i's)
    const int j  = tid & 63;
    const int ch = tid >> 6;
    {
        const int i0 = ch * 64;
        float s = 0.f;
        #pragma unroll 8
        for (int i = 0; i < 64; i++) {
            s = fmaf(s_x[i0 + i], W1[(i0 + i) * H2 + j], s);
        }
        s_p1[ch][j] = s;
    }
    __syncthreads();
    if (tid < H2) {
        float s = b1[tid];
        #pragma unroll
        for (int r = 0; r < 8; r++) s += s_p1[r][tid];
        s_h1[tid] = (s >= 0.f) ? s : a1 * s;
    }
    __syncthreads();

    // layer 2: 8 chunks x 8 i's
    {
        const int i0 = ch * 8;
        float s = 0.f;
        #pragma unroll
        for (int i = 0; i < 8; i++) {
            s = fmaf(s_h1[i0 + i], W2[(i0 + i) * H2 + j], s);
        }
        s_p1[ch][j] = s;
    }
    __syncthreads();
    if (tid < H2) {
        float s = b2[tid];
        #pragma unroll
        for (int r = 0; r < 8; r++) s += s_p1[r][tid];
        s = (s >= 0.f) ? s : a2 * s;
        out[bag * H2 + tid] = s;
    }
}

// ---------------------------------------------------------------------------
// Kernel 2: one block per (b,k). Bitmap intersection + cooperative eval dots.
// ---------------------------------------------------------------------------
__global__ __launch_bounds__(128) void text_sim_kernel(
    const int* __restrict__ qbf, const int* __restrict__ pbf,
    const float* __restrict__ q_eval, const float* __restrict__ p_eval,
    const float* __restrict__ qh_ws, const float* __restrict__ ph_ws,
    const float* __restrict__ ind_ap,
    float* __restrict__ text_out)
{
    const int blk = blockIdx.x;
    const int b   = blk >> 5;
    const int k   = blk & 31;
    const int tid = threadIdx.x;
    const int lane = tid & 63;
    const int wave = tid >> 6;

    __shared__ unsigned int bm[256];   // 8192-bit membership
    __shared__ float s_qh[H2];
    __shared__ float s_ph[H2];
    __shared__ int   s_hitv[L_SZ];
    __shared__ int   s_nh;
    __shared__ float s_wp[2];

    bm[tid] = 0u; bm[tid + 128] = 0u;
    if (tid == 0) s_nh = 0;
    if (tid < H2)  s_qh[tid] = qh_ws[b * H2 + tid];
    else           s_ph[tid - H2] = ph_ws[(b * K_SZ + k) * H2 + (tid - H2)];

    int pv = pbf[(b * K_SZ + k) * L_SZ + tid];
    if ((unsigned)pv < (unsigned)PAD_V)
        atomicOr(&bm[pv >> 5], 1u << (pv & 31));
    __syncthreads();

    // test query values, compact hits
    {
        int v = qbf[b * L_SZ + tid];
        bool hit = ((unsigned)v < (unsigned)PAD_V) &&
                   ((bm[v >> 5] >> (v & 31)) & 1u);
        if (hit) {
            int pos = atomicAdd(&s_nh, 1);
            s_hitv[pos] = v;
        }
    }
    __syncthreads();

    const int nh = s_nh;
    const float ind_a = *ind_ap;
    float local = 0.f;

    for (int hh = wave; hh < nh; hh += 2) {
        int v = s_hitv[hh];
        float qd = s_qh[lane] * q_eval[(size_t)v * H2 + lane];
        float pd = s_ph[lane] * p_eval[(size_t)v * H2 + lane];
        #pragma unroll
        for (int m = 1; m < 64; m <<= 1) {
            qd += __shfl_xor(qd, m);
            pd += __shfl_xor(pd, m);
        }
        qd = (qd >= 0.f) ? qd : ind_a * qd;
        pd = (pd >= 0.f) ? pd : ind_a * pd;
        local += (qd + 1.f) * (pd + 1.f);
    }
    if (lane == 0) s_wp[wave] = local;
    __syncthreads();
    if (tid == 0) text_out[blk] = s_wp[0] + s_wp[1];
}

// ---------------------------------------------------------------------------
// Kernel 3: epilogue — one block per b (32 lanes): max, normalize, sigmoid, dist.
// ---------------------------------------------------------------------------
__global__ __launch_bounds__(64) void epilogue_kernel(
    const float* __restrict__ text_ws,
    const float* __restrict__ qloc, const float* __restrict__ ploc,
    const float* __restrict__ ap, const float* __restrict__ bp,
    const float* __restrict__ cp, const float* __restrict__ dp,
    float* __restrict__ out)
{
    const int b = blockIdx.x;
    const int t = threadIdx.x;   // 0..63, only 0..31 store
    const int kk = t & 31;

    float ts_raw = text_ws[b * K_SZ + kk];
    float mx = ts_raw;
    #pragma unroll
    for (int m = 1; m < 32; m <<= 1) mx = fmaxf(mx, __shfl_xor(mx, m));

    float qx = qloc[b * 2], qy = qloc[b * 2 + 1];
    float px = ploc[(b * K_SZ + kk) * 2];
    float py = ploc[(b * K_SZ + kk) * 2 + 1];
    float dx = qx - px, dy = qy - py;
    float dist = sqrtf(dx * dx + dy * dy);
    float ds = -logf(dist + 1.0f);

    float ts = (2.0f * ts_raw - mx) / (mx + 1e-6f);
    float A = *ap, Bb = *bp, C = *cp, D = *dp;
    float sig = 1.0f / (1.0f + expf(-(A * ts + Bb)));
    if (t < 32) out[b * K_SZ + kk] = (C - sig) * (ds - D);
}

extern "C" void kernel_launch(void* const* d_in, const int* in_sizes, int n_in,
                              void* d_out, int out_size, void* d_ws, size_t ws_size,
                              hipStream_t stream) {
    const int*   qbf      = (const int*)d_in[0];
    const int*   pbf      = (const int*)d_in[1];
    const float* qloc     = (const float*)d_in[2];
    const float* ploc     = (const float*)d_in[3];
    const float* codebook = (const float*)d_in[4];
    const float* qW1      = (const float*)d_in[5];
    const float* qb1      = (const float*)d_in[6];
    const float* qW2      = (const float*)d_in[7];
    const float* qb2      = (const float*)d_in[8];
    const float* pW1      = (const float*)d_in[9];
    const float* pb1      = (const float*)d_in[10];
    const float* pW2      = (const float*)d_in[11];
    const float* pb2      = (const float*)d_in[12];
    const float* q_eval   = (const float*)d_in[13];
    const float* p_eval   = (const float*)d_in[14];
    const float* qa0      = (const float*)d_in[15];
    const float* qa1      = (const float*)d_in[16];
    const float* qa2      = (const float*)d_in[17];
    const float* pa0      = (const float*)d_in[18];
    const float* pa1      = (const float*)d_in[19];
    const float* pa2      = (const float*)d_in[20];
    const float* ind_a    = (const float*)d_in[21];
    const float* a        = (const float*)d_in[22];
    const float* bsc      = (const float*)d_in[23];
    const float* c        = (const float*)d_in[24];
    const float* d        = (const float*)d_in[25];

    float* qh   = (float*)d_ws;                   // 32*64
    float* ph   = qh + B_SZ * H2;                 // 1024*64
    float* text = ph + B_SZ * K_SZ * H2;          // 1024

    emb_mlp_kernel<<<B_SZ + B_SZ * K_SZ, 512, 0, stream>>>(
        qbf, pbf, codebook,
        qW1, qb1, qW2, qb2, pW1, pb1, pW2, pb2,
        qa0, qa1, qa2, pa0, pa1, pa2,
        qh, ph);

    text_sim_kernel<<<B_SZ * K_SZ, 128, 0, stream>>>(
        qbf, pbf, q_eval, p_eval, qh, ph, ind_a, text);

    epilogue_kernel<<<B_SZ, 64, 0, stream>>>(
        text, qloc, ploc, a, bsc, c, d, (float*)d_out);
}

// Round 6
// 154.335 us; speedup vs baseline: 1.1488x; 1.0077x over previous
//
#include <hip/hip_runtime.h>
#include <hip/hip_bf16.h>

#define PAD_V 8192
#define H1 512
#define H2 64
#define B_SZ 32
#define K_SZ 32
#define L_SZ 128
#define EMB_BLOCKS (B_SZ + B_SZ * K_SZ)       // 1056
#define ISECT_BLOCKS ((B_SZ * K_SZ) / 4)      // 256: 4 (b,k) pairs per block

// ---------------------------------------------------------------------------
// Kernel 1 (front): two roles by blockIdx.
//  - blocks 0..1055: one bag each. embedding_bag_mean + prelu + 2-layer MLP.
//    (blocks 0..31 query, 32..1055 poi)
//  - blocks 1056..1311: bitmap intersection + hit compaction for 4 (b,k)
//    pairs each -> nh_ws / hits_ws. Rides in the gather's latency shadow.
// NOTE (R4 post-mortem): no device-scope done-counter fusion — 1024
// simultaneous device atomics + threadfence cost +22 us. Cross-kernel
// ws handoff at dispatch boundary is free instead.
// ---------------------------------------------------------------------------
__global__ __launch_bounds__(512, 8) void front_kernel(
    const int* __restrict__ qbf, const int* __restrict__ pbf,
    const float* __restrict__ codebook,
    const float* __restrict__ qW1, const float* __restrict__ qb1,
    const float* __restrict__ qW2, const float* __restrict__ qb2,
    const float* __restrict__ pW1, const float* __restrict__ pb1,
    const float* __restrict__ pW2, const float* __restrict__ pb2,
    const float* __restrict__ qa0p, const float* __restrict__ qa1p, const float* __restrict__ qa2p,
    const float* __restrict__ pa0p, const float* __restrict__ pa1p, const float* __restrict__ pa2p,
    float* __restrict__ qh_out, float* __restrict__ ph_out,
    int* __restrict__ nh_ws, int* __restrict__ hits_ws)
{
    const int tid = threadIdx.x;

    // ---- role B: intersection blocks ----
    if (blockIdx.x >= EMB_BLOCKS) {
        __shared__ unsigned int bm4[4][256];   // 4 KB
        __shared__ int s_nh4[4];
        __shared__ int s_hit4[4][L_SZ];        // 2 KB

        const int pair0 = (blockIdx.x - EMB_BLOCKS) * 4;
        const int sub = tid >> 7;              // 0..3
        const int t   = tid & 127;
        const int pair = pair0 + sub;
        const int b = pair >> 5;

        bm4[sub][t] = 0u; bm4[sub][t + 128] = 0u;
        if (t == 0) s_nh4[sub] = 0;
        __syncthreads();

        int pv = pbf[pair * L_SZ + t];
        if ((unsigned)pv < (unsigned)PAD_V)
            atomicOr(&bm4[sub][pv >> 5], 1u << (pv & 31));
        __syncthreads();

        int v = qbf[b * L_SZ + t];
        bool hit = ((unsigned)v < (unsigned)PAD_V) &&
                   ((bm4[sub][v >> 5] >> (v & 31)) & 1u);
        if (hit) {
            int pos = atomicAdd(&s_nh4[sub], 1);
            s_hit4[sub][pos] = v;
        }
        __syncthreads();

        if (t == 0) nh_ws[pair] = s_nh4[sub];
        if (t < s_nh4[sub]) hits_ws[pair * L_SZ + t] = s_hit4[sub][t];
        return;
    }

    // ---- role A: embedding + MLP ----
    const bool is_q = (blockIdx.x < B_SZ);
    const int* idx_base;
    int bag;
    const float *W1, *b1, *W2, *b2;
    float a0, a1, a2;
    float* out;
    if (is_q) {
        idx_base = qbf; bag = blockIdx.x;
        W1 = qW1; b1 = qb1; W2 = qW2; b2 = qb2;
        a0 = *qa0p; a1 = *qa1p; a2 = *qa2p;
        out = qh_out;
    } else {
        idx_base = pbf; bag = blockIdx.x - B_SZ;
        W1 = pW1; b1 = pb1; W2 = pW2; b2 = pb2;
        a0 = *pa0p; a1 = *pa1p; a2 = *pa2p;
        out = ph_out;
    }

    __shared__ int   s_idx[L_SZ];
    __shared__ int   s_cntp[2];
    __shared__ float s_red[3][L_SZ][4];   // 6 KB
    __shared__ float s_x[H1];             // 2 KB
    __shared__ float s_p1[32][H2];        // 8 KB
    __shared__ float s_h1[H2];

    if (tid < L_SZ) s_idx[tid] = idx_base[bag * L_SZ + tid];
    __syncthreads();

    if (tid < L_SZ) {
        unsigned long long bal = __ballot(s_idx[tid] != PAD_V);
        if ((tid & 63) == 0) s_cntp[tid >> 6] = __popcll(bal);
    }

    // gather: quarter q = tid>>7 owns 32 rows; g = tid&127 is the 16B chunk
    const int g = tid & 127;
    const int q = tid >> 7;
    const float4* cb4 = (const float4*)codebook;
    float ax = 0.f, ay = 0.f, az = 0.f, aw = 0.f;
    #pragma unroll 8
    for (int l = 0; l < 32; l++) {
        int v = s_idx[q * 32 + l];
        float m = (v != PAD_V) ? 1.0f : 0.0f;
        float4 r = cb4[(size_t)v * 128 + g];
        ax = fmaf(m, r.x, ax);
        ay = fmaf(m, r.y, ay);
        az = fmaf(m, r.z, az);
        aw = fmaf(m, r.w, aw);
    }
    if (q != 0) {
        s_red[q - 1][g][0] = ax; s_red[q - 1][g][1] = ay;
        s_red[q - 1][g][2] = az; s_red[q - 1][g][3] = aw;
    }
    __syncthreads();
    if (q == 0) {
        int cnt = s_cntp[0] + s_cntp[1];
        float inv = (cnt > 0) ? 1.0f / (float)cnt : 0.0f;
        float e0 = (ax + s_red[0][g][0] + s_red[1][g][0] + s_red[2][g][0]) * inv;
        float e1 = (ay + s_red[0][g][1] + s_red[1][g][1] + s_red[2][g][1]) * inv;
        float e2 = (az + s_red[0][g][2] + s_red[1][g][2] + s_red[2][g][2]) * inv;
        float e3 = (aw + s_red[0][g][3] + s_red[1][g][3] + s_red[2][g][3]) * inv;
        s_x[4 * g + 0] = (e0 >= 0.f) ? e0 : a0 * e0;
        s_x[4 * g + 1] = (e1 >= 0.f) ? e1 : a0 * e1;
        s_x[4 * g + 2] = (e2 >= 0.f) ? e2 : a0 * e2;
        s_x[4 * g + 3] = (e3 >= 0.f) ? e3 : a0 * e3;
    }
    __syncthreads();

    // layer 1: thread = (i-chunk ch = tid>>4 of 32, col-quad j4 = tid&15)
    // 16 i's per chunk, float4 weight loads (cols 4*j4..4*j4+3)
    const int j4 = tid & 15;
    const int ch = tid >> 4;
    const float4* W1v = (const float4*)W1;
    {
        const int i0 = ch * 16;
        float sx = 0.f, sy = 0.f, sz = 0.f, sw = 0.f;
        #pragma unroll
        for (int i = 0; i < 16; i++) {
            float x = s_x[i0 + i];
            float4 w = W1v[(size_t)(i0 + i) * 16 + j4];
            sx = fmaf(x, w.x, sx);
            sy = fmaf(x, w.y, sy);
            sz = fmaf(x, w.z, sz);
            sw = fmaf(x, w.w, sw);
        }
        s_p1[ch][4 * j4 + 0] = sx;
        s_p1[ch][4 * j4 + 1] = sy;
        s_p1[ch][4 * j4 + 2] = sz;
        s_p1[ch][4 * j4 + 3] = sw;
    }
    __syncthreads();
    if (tid < H2) {
        float s = b1[tid];
        #pragma unroll
        for (int r = 0; r < 32; r++) s += s_p1[r][tid];
        s_h1[tid] = (s >= 0.f) ? s : a1 * s;
    }
    __syncthreads();

    // layer 2: 32 chunks x 2 i's, float4 weight loads
    const float4* W2v = (const float4*)W2;
    {
        const int i0 = ch * 2;
        float sx = 0.f, sy = 0.f, sz = 0.f, sw = 0.f;
        #pragma unroll
        for (int i = 0; i < 2; i++) {
            float x = s_h1[i0 + i];
            float4 w = W2v[(size_t)(i0 + i) * 16 + j4];
            sx = fmaf(x, w.x, sx);
            sy = fmaf(x, w.y, sy);
            sz = fmaf(x, w.z, sz);
            sw = fmaf(x, w.w, sw);
        }
        s_p1[ch][4 * j4 + 0] = sx;
        s_p1[ch][4 * j4 + 1] = sy;
        s_p1[ch][4 * j4 + 2] = sz;
        s_p1[ch][4 * j4 + 3] = sw;
    }
    __syncthreads();
    if (tid < H2) {
        float s = b2[tid];
        #pragma unroll
        for (int r = 0; r < 32; r++) s += s_p1[r][tid];
        s = (s >= 0.f) ? s : a2 * s;
        out[bag * H2 + tid] = s;
    }
}

// ---------------------------------------------------------------------------
// Kernel 2: one wave per (b,k). Pure dot phase over precompacted hits.
// ---------------------------------------------------------------------------
__global__ __launch_bounds__(64) void text_sim_kernel(
    const float* __restrict__ q_eval, const float* __restrict__ p_eval,
    const float* __restrict__ qh_ws, const float* __restrict__ ph_ws,
    const int* __restrict__ nh_ws, const int* __restrict__ hits_ws,
    const float* __restrict__ ind_ap,
    float* __restrict__ text_out)
{
    const int blk = blockIdx.x;      // (b,k) pair
    const int b    = blk >> 5;
    const int lane = threadIdx.x;    // 0..63

    const float qh = qh_ws[b * H2 + lane];
    const float ph = ph_ws[blk * H2 + lane];
    const int   nh = nh_ws[blk];
    const float ind_a = *ind_ap;

    float local = 0.f;
    for (int hh = 0; hh < nh; hh++) {
        int v = hits_ws[blk * L_SZ + hh];
        float qd = qh * q_eval[(size_t)v * H2 + lane];
        float pd = ph * p_eval[(size_t)v * H2 + lane];
        #pragma unroll
        for (int m = 1; m < 64; m <<= 1) {
            qd += __shfl_xor(qd, m);
            pd += __shfl_xor(pd, m);
        }
        qd = (qd >= 0.f) ? qd : ind_a * qd;
        pd = (pd >= 0.f) ? pd : ind_a * pd;
        local += (qd + 1.f) * (pd + 1.f);
    }
    if (lane == 0) text_out[blk] = local;
}

// ---------------------------------------------------------------------------
// Kernel 3: epilogue — one block per b: max, normalize, sigmoid, distance.
// ---------------------------------------------------------------------------
__global__ __launch_bounds__(64) void epilogue_kernel(
    const float* __restrict__ text_ws,
    const float* __restrict__ qloc, const float* __restrict__ ploc,
    const float* __restrict__ ap, const float* __restrict__ bp,
    const float* __restrict__ cp, const float* __restrict__ dp,
    float* __restrict__ out)
{
    const int b = blockIdx.x;
    const int t = threadIdx.x;
    const int kk = t & 31;

    float ts_raw = text_ws[b * K_SZ + kk];
    float mx = ts_raw;
    #pragma unroll
    for (int m = 1; m < 32; m <<= 1) mx = fmaxf(mx, __shfl_xor(mx, m));

    float qx = qloc[b * 2], qy = qloc[b * 2 + 1];
    float px = ploc[(b * K_SZ + kk) * 2];
    float py = ploc[(b * K_SZ + kk) * 2 + 1];
    float dx = qx - px, dy = qy - py;
    float dist = sqrtf(dx * dx + dy * dy);
    float ds = -logf(dist + 1.0f);

    float ts = (2.0f * ts_raw - mx) / (mx + 1e-6f);
    float A = *ap, Bb = *bp, C = *cp, D = *dp;
    float sig = 1.0f / (1.0f + expf(-(A * ts + Bb)));
    if (t < 32) out[b * K_SZ + kk] = (C - sig) * (ds - D);
}

extern "C" void kernel_launch(void* const* d_in, const int* in_sizes, int n_in,
                              void* d_out, int out_size, void* d_ws, size_t ws_size,
                              hipStream_t stream) {
    const int*   qbf      = (const int*)d_in[0];
    const int*   pbf      = (const int*)d_in[1];
    const float* qloc     = (const float*)d_in[2];
    const float* ploc     = (const float*)d_in[3];
    const float* codebook = (const float*)d_in[4];
    const float* qW1      = (const float*)d_in[5];
    const float* qb1      = (const float*)d_in[6];
    const float* qW2      = (const float*)d_in[7];
    const float* qb2      = (const float*)d_in[8];
    const float* pW1      = (const float*)d_in[9];
    const float* pb1      = (const float*)d_in[10];
    const float* pW2      = (const float*)d_in[11];
    const float* pb2      = (const float*)d_in[12];
    const float* q_eval   = (const float*)d_in[13];
    const float* p_eval   = (const float*)d_in[14];
    const float* qa0      = (const float*)d_in[15];
    const float* qa1      = (const float*)d_in[16];
    const float* qa2      = (const float*)d_in[17];
    const float* pa0      = (const float*)d_in[18];
    const float* pa1      = (const float*)d_in[19];
    const float* pa2      = (const float*)d_in[20];
    const float* ind_a    = (const float*)d_in[21];
    const float* a        = (const float*)d_in[22];
    const float* bsc      = (const float*)d_in[23];
    const float* c        = (const float*)d_in[24];
    const float* d        = (const float*)d_in[25];

    float* qh   = (float*)d_ws;                   // 32*64
    float* ph   = qh + B_SZ * H2;                 // 1024*64
    float* text = ph + B_SZ * K_SZ * H2;          // 1024
    int*   nh   = (int*)(text + B_SZ * K_SZ);     // 1024
    int*   hits = nh + B_SZ * K_SZ;               // 1024*128

    front_kernel<<<EMB_BLOCKS + ISECT_BLOCKS, 512, 0, stream>>>(
        qbf, pbf, codebook,
        qW1, qb1, qW2, qb2, pW1, pb1, pW2, pb2,
        qa0, qa1, qa2, pa0, pa1, pa2,
        qh, ph, nh, hits);

    text_sim_kernel<<<B_SZ * K_SZ, 64, 0, stream>>>(
        q_eval, p_eval, qh, ph, nh, hits, ind_a, text);

    epilogue_kernel<<<B_SZ, 64, 0, stream>>>(
        text, qloc, ploc, a, bsc, c, d, (float*)d_out);
}